// Round 1
// baseline (599.764 us; speedup 1.0000x reference)
//
#include <hip/hip_runtime.h>
#include <math.h>

#define ROW_N 2048
#define KSEL 10

// One block per row of 2048 floats. Each thread owns 8 elements in registers:
//   r in [0,4): global pos 4*tid + r          (first float4, bytes [0, 4096))
//   r in [4,8): global pos 1024 + 4*tid + r-4 (second float4, bytes [4096, 8192))
// Both loads/stores are perfectly coalesced across the wave.
__global__ __launch_bounds__(256) void topk_softmax_kernel(
    const float* __restrict__ in, float* __restrict__ out)
{
    const int tid = threadIdx.x;
    const size_t base = (size_t)blockIdx.x * ROW_N;

    __shared__ float s_row[ROW_N];   // 8 KB staging for scatter + coalesced store
    __shared__ float s_wval[4];
    __shared__ int   s_widx[4];
    __shared__ float s_red[4];
    __shared__ float s_topv[KSEL];
    __shared__ int   s_topi[KSEL];
    __shared__ float s_p[KSEL];
    __shared__ int   s_bidx;

    const float4 a = reinterpret_cast<const float4*>(in + base)[tid];
    const float4 b = reinterpret_cast<const float4*>(in + base)[tid + 256];
    float v[8] = {a.x, a.y, a.z, a.w, b.x, b.y, b.z, b.w};

    const int lane = tid & 63;
    const int wave = tid >> 6;

    // ---- 10 iterations of block-wide argmax (tie-break: lowest index) ----
    for (int it = 0; it < KSEL; ++it) {
        // local argmax over 8 registers; ascending r => ascending global pos,
        // so strict '>' keeps the lowest index on ties.
        float bv = v[0]; int br = 0;
        #pragma unroll
        for (int r = 1; r < 8; ++r)
            if (v[r] > bv) { bv = v[r]; br = r; }
        int bidx = (br < 4) ? (4 * tid + br) : (1024 + 4 * tid + (br - 4));

        // wave64 shuffle reduce with index tie-break
        #pragma unroll
        for (int off = 32; off > 0; off >>= 1) {
            float ov = __shfl_down(bv, off);
            int   oi = __shfl_down(bidx, off);
            if (ov > bv || (ov == bv && oi < bidx)) { bv = ov; bidx = oi; }
        }
        if (lane == 0) { s_wval[wave] = bv; s_widx[wave] = bidx; }
        __syncthreads();
        if (tid == 0) {
            float wv = s_wval[0]; int wi = s_widx[0];
            #pragma unroll
            for (int w = 1; w < 4; ++w) {
                float ov = s_wval[w]; int oi = s_widx[w];
                if (ov > wv || (ov == wv && oi < wi)) { wv = ov; wi = oi; }
            }
            s_topv[it] = wv; s_topi[it] = wi; s_bidx = wi;
        }
        __syncthreads();
        // owner thread masks the extracted element out of the remaining set
        const int wi = s_bidx;
        const int ot = (wi < 1024) ? (wi >> 2) : ((wi - 1024) >> 2);
        if (ot == tid) {
            const int orr = (wi < 1024) ? (wi & 3) : (4 + (wi & 3));
            v[orr] = -INFINITY;
        }
    }

    // ---- softmax over the 10 extracted values (s_topv[0] is the global max) ----
    if (tid == 0) {
        const float m = s_topv[0];
        float e[KSEL]; float s = 0.f;
        #pragma unroll
        for (int j = 0; j < KSEL; ++j) { e[j] = __expf(s_topv[j] - m); s += e[j]; }
        const float inv = 0.9f / s;   // (1 - SMOOTHING)
        #pragma unroll
        for (int j = 0; j < KSEL; ++j) s_p[j] = e[j] * inv;
    }

    // ---- softmax over the remaining 2038 (extracted slots hold -inf -> exp=0) ----
    float bm = v[0];
    #pragma unroll
    for (int r = 1; r < 8; ++r) bm = fmaxf(bm, v[r]);
    #pragma unroll
    for (int off = 32; off > 0; off >>= 1)
        bm = fmaxf(bm, __shfl_down(bm, off));
    if (lane == 0) s_red[wave] = bm;
    __syncthreads();
    const float m_rem = fmaxf(fmaxf(s_red[0], s_red[1]), fmaxf(s_red[2], s_red[3]));

    float e[8]; float loc = 0.f;
    #pragma unroll
    for (int r = 0; r < 8; ++r) { e[r] = __expf(v[r] - m_rem); loc += e[r]; }
    __syncthreads();   // everyone has read s_red (max) before it is reused for sums
    #pragma unroll
    for (int off = 32; off > 0; off >>= 1)
        loc += __shfl_down(loc, off);
    if (lane == 0) s_red[wave] = loc;
    __syncthreads();
    const float s_rem = (s_red[0] + s_red[1]) + (s_red[2] + s_red[3]);
    const float inv_rem = 0.1f / s_rem;   // SMOOTHING

    // stage remaining-softmax outputs in LDS, scatter top-k probs, store coalesced
    #pragma unroll
    for (int r = 0; r < 4; ++r) s_row[4 * tid + r] = e[r] * inv_rem;
    #pragma unroll
    for (int r = 0; r < 4; ++r) s_row[1024 + 4 * tid + r] = e[4 + r] * inv_rem;
    __syncthreads();
    if (tid < KSEL) s_row[s_topi[tid]] = s_p[tid];
    __syncthreads();

    float4* o = reinterpret_cast<float4*>(out + base);
    const float4* sr = reinterpret_cast<const float4*>(s_row);
    o[tid]       = sr[tid];
    o[tid + 256] = sr[tid + 256];
}

extern "C" void kernel_launch(void* const* d_in, const int* in_sizes, int n_in,
                              void* d_out, int out_size, void* d_ws, size_t ws_size,
                              hipStream_t stream) {
    const float* logits = (const float*)d_in[0];
    float* out = (float*)d_out;
    // d_in[1] is dim (==3, the last axis) — layout already has softmax axis contiguous.
    const int rows = out_size / ROW_N;   // 2*8*2048 = 32768
    topk_softmax_kernel<<<dim3(rows), dim3(256), 0, stream>>>(logits, out);
}

// Round 2
// 500.577 us; speedup vs baseline: 1.1981x; 1.1981x over previous
//
#include <hip/hip_runtime.h>
#include <math.h>

#define ROW_N 2048
#define KSEL 10
#define CAP 256

// One block per row of 2048 f32. Each thread owns 8 elements in registers:
//   r in [0,4): global pos 4*tid + r          (first float4)
//   r in [4,8): global pos 1024 + 4*tid + r-4 (second float4)
// Top-10 selection: 11-bit radix histogram -> threshold bin -> collect ~13-25
// candidates as packed u64 keys -> exact top-10 on one wave. Tie-break
// (lowest index, per lax.top_k) is exact via key = (ord_val<<16)|(2047-idx).
__global__ __launch_bounds__(256) void topk_softmax_kernel(
    const float* __restrict__ in, float* __restrict__ out)
{
    const int tid  = threadIdx.x;
    const int lane = tid & 63;
    const int wave = tid >> 6;
    const size_t base = (size_t)blockIdx.x * ROW_N;

    __shared__ uint32_t s_hist[ROW_N];            // 8 KB; reused as float staging later
    __shared__ unsigned long long s_cand[CAP];    // 2 KB
    __shared__ int s_cc;
    __shared__ uint32_t s_T;
    __shared__ unsigned long long s_kmin;
    __shared__ float s_cval;
    __shared__ float s_ws[4];
    __shared__ int   s_pi[KSEL];
    __shared__ float s_pv[KSEL];

    const float4 a = reinterpret_cast<const float4*>(in + base)[tid];
    const float4 b = reinterpret_cast<const float4*>(in + base)[tid + 256];
    float v[8] = {a.x, a.y, a.z, a.w, b.x, b.y, b.z, b.w};

    // order-preserving uint transform
    uint32_t ov[8];
    #pragma unroll
    for (int r = 0; r < 8; ++r) {
        uint32_t u = __float_as_uint(v[r]);
        ov[r] = u ^ ((uint32_t)((int32_t)u >> 31) | 0x80000000u);
    }

    // zero histogram + candidate counter
    uint4 z4 = make_uint4(0, 0, 0, 0);
    reinterpret_cast<uint4*>(s_hist)[tid]       = z4;
    reinterpret_cast<uint4*>(s_hist)[tid + 256] = z4;
    if (tid == 0) s_cc = 0;
    __syncthreads();

    // 11-bit histogram (top 11 bits of ordered uint)
    #pragma unroll
    for (int r = 0; r < 8; ++r)
        atomicAdd(&s_hist[ov[r] >> 21], 1u);
    __syncthreads();

    // wave 0: find smallest bin T with count(bin >= T) >= KSEL
    if (wave == 0) {
        uint32_t c = 0;
        const uint4* h4 = reinterpret_cast<const uint4*>(s_hist);
        #pragma unroll
        for (int j = 0; j < 8; ++j) {
            uint4 q = h4[lane * 8 + j];
            c += q.x + q.y + q.z + q.w;           // count over bins [32*lane, 32*lane+32)
        }
        uint32_t s = c;                            // inclusive suffix over chunks
        #pragma unroll
        for (int off = 1; off < 64; off <<= 1) {
            uint32_t t = __shfl_down(s, off);
            s += (lane + off < 64) ? t : 0;
        }
        unsigned long long m = __ballot(s >= KSEL);       // prefix set [0..L]
        int L = 63 - __clzll((long long)m);                // threshold chunk
        uint32_t above = (L < 63) ? __shfl(s, L + 1) : 0;  // elems in chunks > L
        uint32_t hb = (lane < 32) ? s_hist[L * 32 + lane] : 0;
        uint32_t s2 = hb;                          // suffix within chunk
        #pragma unroll
        for (int off = 1; off < 32; off <<= 1) {
            uint32_t t = __shfl_down(s2, off);
            s2 += (lane + off < 32) ? t : 0;
        }
        unsigned long long m2 = __ballot((lane < 32) && (above + s2 >= KSEL));
        int l2 = 63 - __clzll((long long)m2);
        if (lane == 0) s_T = (uint32_t)(L * 32 + l2);
    }
    __syncthreads();

    // collect candidates (bin >= T) as packed keys
    const uint32_t T = s_T;
    #pragma unroll
    for (int r = 0; r < 8; ++r) {
        if ((ov[r] >> 21) >= T) {
            int idx = (r < 4) ? (4 * tid + r) : (1024 + 4 * tid + (r - 4));
            int pos = atomicAdd(&s_cc, 1);
            if (pos < CAP)
                s_cand[pos] = ((unsigned long long)ov[r] << 16) |
                              (unsigned)(2047 - idx);
        }
    }
    __syncthreads();

    // wave 0: exact top-10 over candidates + top-k softmax
    if (wave == 0) {
        int C = s_cc; if (C > CAP) C = CAP;
        unsigned long long kk[4];
        #pragma unroll
        for (int j = 0; j < 4; ++j)
            kk[j] = (j * 64 + lane < C) ? s_cand[j * 64 + lane] : 0ULL;

        unsigned long long mykey = 0;
        #pragma unroll
        for (int it = 0; it < KSEL; ++it) {
            unsigned long long bk = kk[0]; int bj = 0;
            #pragma unroll
            for (int j = 1; j < 4; ++j)
                if (kk[j] > bk) { bk = kk[j]; bj = j; }
            unsigned long long wk = bk;
            #pragma unroll
            for (int off = 32; off > 0; off >>= 1) {
                unsigned long long o = __shfl_down(wk, off);
                if (o > wk) wk = o;
            }
            wk = __shfl(wk, 0);                   // broadcast winner
            if (bk == wk) {                        // winner lane clears (keys unique)
                if      (bj == 0) kk[0] = 0;
                else if (bj == 1) kk[1] = 0;
                else if (bj == 2) kk[2] = 0;
                else              kk[3] = 0;
            }
            if (lane == it) mykey = wk;            // lane it keeps it-th largest
        }

        uint32_t ovk  = (uint32_t)(mykey >> 16);
        uint32_t bits = ovk ^ ((ovk & 0x80000000u) ? 0x80000000u : 0xFFFFFFFFu);
        float myval = __uint_as_float(bits);
        int   myidx = 2047 - (int)(mykey & 0xFFFFull);

        float vmax = __shfl(myval, 0);             // largest value
        float e = (lane < KSEL) ? __expf(myval - vmax) : 0.f;
        float ssum = e;
        #pragma unroll
        for (int off = 32; off > 0; off >>= 1) ssum += __shfl_down(ssum, off);
        ssum = __shfl(ssum, 0);
        if (lane < KSEL) { s_pi[lane] = myidx; s_pv[lane] = e * (0.9f / ssum); }
        if (lane == KSEL - 1) { s_kmin = mykey; s_cval = myval; }  // 10th largest
    }
    __syncthreads();

    // remaining softmax: mask = key < key_of_10th; shift by 10th value
    // (softmax is shift-invariant; avoids a block max-reduce entirely)
    const unsigned long long kmin = s_kmin;
    const float cshift = s_cval;
    float e[8]; float loc = 0.f;
    #pragma unroll
    for (int r = 0; r < 8; ++r) {
        int idx = (r < 4) ? (4 * tid + r) : (1024 + 4 * tid + (r - 4));
        unsigned long long key = ((unsigned long long)ov[r] << 16) |
                                 (unsigned)(2047 - idx);
        float ex = __expf(v[r] - cshift);
        e[r] = (key < kmin) ? ex : 0.f;
        loc += e[r];
    }
    #pragma unroll
    for (int off = 32; off > 0; off >>= 1) loc += __shfl_down(loc, off);
    if (lane == 0) s_ws[wave] = loc;
    __syncthreads();
    const float s_rem = (s_ws[0] + s_ws[1]) + (s_ws[2] + s_ws[3]);
    const float inv_rem = 0.1f / s_rem;

    // stage in LDS (reusing histogram memory), scatter top-k, coalesced store
    float* s_row = reinterpret_cast<float*>(s_hist);
    #pragma unroll
    for (int r = 0; r < 4; ++r) s_row[4 * tid + r] = e[r] * inv_rem;
    #pragma unroll
    for (int r = 0; r < 4; ++r) s_row[1024 + 4 * tid + r] = e[4 + r] * inv_rem;
    __syncthreads();
    if (tid < KSEL) s_row[s_pi[tid]] = s_pv[tid];
    __syncthreads();

    float4* o = reinterpret_cast<float4*>(out + base);
    const float4* sr = reinterpret_cast<const float4*>(s_row);
    o[tid]       = sr[tid];
    o[tid + 256] = sr[tid + 256];
}

extern "C" void kernel_launch(void* const* d_in, const int* in_sizes, int n_in,
                              void* d_out, int out_size, void* d_ws, size_t ws_size,
                              hipStream_t stream) {
    const float* logits = (const float*)d_in[0];
    float* out = (float*)d_out;
    const int rows = out_size / ROW_N;   // 2*8*2048 = 32768
    topk_softmax_kernel<<<dim3(rows), dim3(256), 0, stream>>>(logits, out);
}